// Round 7
// baseline (691.801 us; speedup 1.0000x reference)
//
#include <hip/hip_runtime.h>
#include <hip/hip_bf16.h>
#include <math.h>

#define E_EDGES   1000000
#define LN_EPS    1e-5f
#define TILES_TOT 7813       // ceil(1e6 / 128)
#define TPB_TILES 31         // tiles per block at grid=256

typedef unsigned short u16;
typedef __bf16 bf16x8 __attribute__((ext_vector_type(8)));
typedef float  f32x16 __attribute__((ext_vector_type(16)));

__device__ __forceinline__ float lo2f(unsigned d) {
    union { unsigned u; float f; } v; v.u = d << 16; return v.f;
}
__device__ __forceinline__ float hi2f(unsigned d) {
    union { unsigned u; float f; } v; v.u = d & 0xffff0000u; return v.f;
}
__device__ __forceinline__ unsigned pk2(float lo, float hi) {
    __hip_bfloat162 h = __float22bfloat162_rn(make_float2(lo, hi));
    unsigned r; __builtin_memcpy(&r, &h, 4); return r;
}

// ---------------------------------------------------------------------------
// Weight -> bf16 MFMA B-fragment conversion (one-time, ~128 KB in d_out;
// head_mfma overwrites d_out afterwards).
// slot s = (ks*2+nt)*64 + l holds B[k=ks*16+(l>>5)*8+j][n=nt*32+(l&31)].
// ---------------------------------------------------------------------------
__global__ __launch_bounds__(256) void wconv_kernel(
    const float* __restrict__ wr, const float* __restrict__ w0,
    u16* __restrict__ wf)
{
    const int s = blockIdx.x * 256 + threadIdx.x;   // 0..8191
    const int l    = s & 63;
    const int nt   = (s >> 6) & 1;
    const int col  = nt * 32 + (l & 31);
    const int half = l >> 5;
    uint4 pk;
    if (s < 3 * 2560) {
        const int L  = s / 2560;
        const int sl = s % 2560;
        const int kb = (sl >> 7) * 16 + half * 8;
        const float* W = wr + L * 320 * 64;
        pk.x = pk2(W[(kb+0)*64+col], W[(kb+1)*64+col]);
        pk.y = pk2(W[(kb+2)*64+col], W[(kb+3)*64+col]);
        pk.z = pk2(W[(kb+4)*64+col], W[(kb+5)*64+col]);
        pk.w = pk2(W[(kb+6)*64+col], W[(kb+7)*64+col]);
    } else {
        const int sl = s - 3 * 2560;
        const int kb = (sl >> 7) * 16 + half * 8;
        float v[8];
        #pragma unroll
        for (int p = 0; p < 8; ++p) v[p] = (kb + p < 55) ? w0[(kb+p)*64 + col] : 0.f;
        pk.x = pk2(v[0],v[1]); pk.y = pk2(v[2],v[3]);
        pk.z = pk2(v[4],v[5]); pk.w = pk2(v[6],v[7]);
    }
    *(uint4*)&wf[(size_t)s * 8] = pk;
}

// ---------------------------------------------------------------------------
// Pipelined layers 1..3.
// ---------------------------------------------------------------------------
struct GRegs {
    uint4 xv0, xv1, av0, av1, bv0, bv1, cv0, cv1, dv0, dv1;
};

__device__ __forceinline__ void gload(GRegs& g, const u16* __restrict__ xin,
                                      const int* __restrict__ nbr,
                                      int tile, int el, int cq)
{
    size_t e = (size_t)tile * 128 + el;
    if (e >= E_EDGES) e = E_EDGES - 1;          // clamp; stores are guarded
    const int4 n = *(const int4*)(nbr + 4 * e);
    const u16* xr = xin + e * 64            + cq * 16;
    const u16* ar = xin + (size_t)n.x * 64  + cq * 16;
    const u16* br = xin + (size_t)n.y * 64  + cq * 16;
    const u16* cr = xin + (size_t)n.z * 64  + cq * 16;
    const u16* dr = xin + (size_t)n.w * 64  + cq * 16;
    g.xv0 = *(const uint4*)xr;    g.xv1 = *(const uint4*)(xr + 8);
    g.av0 = *(const uint4*)ar;    g.av1 = *(const uint4*)(ar + 8);
    g.bv0 = *(const uint4*)br;    g.bv1 = *(const uint4*)(br + 8);
    g.cv0 = *(const uint4*)cr;    g.cv1 = *(const uint4*)(cr + 8);
    g.dv0 = *(const uint4*)dr;    g.dv1 = *(const uint4*)(dr + 8);
}

// feature build + A-frag LDS write; kstep row = group*4+cq, granule ^= cq.
__device__ __forceinline__ void pack_write(const GRegs& g, u16* __restrict__ afrag,
                                           int el, int cq)
{
    const int mt_g  = el >> 5;                 // 0..3
    const int lane0 = el & 31;
    u16* abase = afrag + (size_t)mt_g * (20 * 64 * 8);
    #pragma unroll
    for (int w8 = 0; w8 < 2; ++w8) {
        const uint4 xv = w8 ? g.xv1 : g.xv0;
        const uint4 av = w8 ? g.av1 : g.av0;
        const uint4 bv = w8 ? g.bv1 : g.bv0;
        const uint4 cv = w8 ? g.cv1 : g.cv0;
        const uint4 dv = w8 ? g.dv1 : g.dv0;
        const int gsw = (lane0 + 32 * w8) ^ cq;
        uint4 g1, g2, g3, g4;
        const unsigned* ap = (const unsigned*)&av;
        const unsigned* bp = (const unsigned*)&bv;
        const unsigned* cp = (const unsigned*)&cv;
        const unsigned* dp = (const unsigned*)&dv;
        unsigned* g1p = (unsigned*)&g1; unsigned* g2p = (unsigned*)&g2;
        unsigned* g3p = (unsigned*)&g3; unsigned* g4p = (unsigned*)&g4;
        #pragma unroll
        for (int i = 0; i < 4; ++i) {
            const float a0 = lo2f(ap[i]), a1 = hi2f(ap[i]);
            const float c0 = lo2f(cp[i]), c1 = hi2f(cp[i]);
            g1p[i] = pk2(a0 - c0, a1 - c1) & 0x7FFF7FFFu;   // |RNE(x)| = RNE(|x|)
            g2p[i] = pk2(a0 + c0, a1 + c1);
            const float b0 = lo2f(bp[i]), b1 = hi2f(bp[i]);
            const float d0 = lo2f(dp[i]), d1 = hi2f(dp[i]);
            g3p[i] = pk2(b0 - d0, b1 - d1) & 0x7FFF7FFFu;
            g4p[i] = pk2(b0 + d0, b1 + d1);
        }
        *(uint4*)(abase + (size_t)(((0*4 + cq) * 64) + gsw) * 8) = xv;
        *(uint4*)(abase + (size_t)(((1*4 + cq) * 64) + gsw) * 8) = g1;
        *(uint4*)(abase + (size_t)(((2*4 + cq) * 64) + gsw) * 8) = g2;
        *(uint4*)(abase + (size_t)(((3*4 + cq) * 64) + gsw) * 8) = g3;
        *(uint4*)(abase + (size_t)(((4*4 + cq) * 64) + gsw) * 8) = g4;
    }
}

__device__ __forceinline__ void store_row(u16* __restrict__ xout, size_t e, int cq,
                                          const float* sv, uint4 res0, uint4 res1,
                                          const float* lgv, const float* lbv)
{
    if (e >= E_EDGES) return;
    u16* outp = xout + e * 64 + cq * 16;
    #pragma unroll
    for (int h = 0; h < 2; ++h) {
        const uint4 res = h ? res1 : res0;
        const unsigned* rr = (const unsigned*)&res;
        uint4 o; unsigned* op = (unsigned*)&o;
        #pragma unroll
        for (int i2 = 0; i2 < 4; ++i2) {
            const int k = h * 8 + i2 * 2;
            const float y0 = fmaxf(fmaf(sv[k],     lgv[k],     lbv[k]),     0.f) + lo2f(rr[i2]);
            const float y1 = fmaxf(fmaf(sv[k + 1], lgv[k + 1], lbv[k + 1]), 0.f) + hi2f(rr[i2]);
            op[i2] = pk2(y0, y1);
        }
        *(uint4*)(outp + h * 8) = o;
    }
}

// 512 thr = 8 waves = (mt 0..3, nt 0..1); 128 edges/tile, TPB_TILES tiles/block.
// LDS: A 80 KB (single buffer) + B 40 KB (staged once) = 120 KB -> 1 block/CU.
// K-loop has NO VMEM (A,B both LDS) so next tile's gathers prefetch cleanly.
__global__ __launch_bounds__(512, 2) void layer_mfma(
    const u16* __restrict__ xin, const int* __restrict__ nbr,
    const u16* __restrict__ wf, const float* __restrict__ bias,
    const float* __restrict__ lng, const float* __restrict__ lnb,
    u16* __restrict__ xout)
{
    __shared__ u16 smem[40960 + 20480];     // A: 80 KB | B: 40 KB
    u16* afrag = smem;
    u16* bfrag = smem + 40960;
    float* ebuf = (float*)smem;             // 128*68*4 = 34.8 KB, aliases A

    const int t  = threadIdx.x;
    const int l  = t & 63;
    const int wv = t >> 6;                  // 0..7
    const int el = t >> 2;                  // 0..127
    const int cq = t & 3;

    const int tile0  = blockIdx.x * TPB_TILES;
    const int ntiles = min(TPB_TILES, TILES_TOT - tile0);
    if (ntiles <= 0) return;

    // hoisted constants (registers, kernel lifetime)
    float lgv[16], lbv[16];
    #pragma unroll
    for (int j = 0; j < 4; ++j) {
        *(float4*)&lgv[j * 4] = *(const float4*)(lng + cq * 16 + j * 4);
        *(float4*)&lbv[j * 4] = *(const float4*)(lnb + cq * 16 + j * 4);
    }
    const int mt = wv >> 1, nt = wv & 1;
    const float bc = bias[nt * 32 + (l & 31)];

    // stage B fragments once (2560 uint4)
    {
        const uint4* src = (const uint4*)wf;
        uint4* dst = (uint4*)bfrag;
        #pragma unroll
        for (int i = 0; i < 5; ++i) dst[t + 512 * i] = src[t + 512 * i];
    }

    GRegs G;
    gload(G, xin, nbr, tile0, el, cq);
    pack_write(G, afrag, el, cq);
    __syncthreads();

    float sv[16];
    uint4 res0 = {}, res1 = {};
    size_t eprev = (size_t)E_EDGES;         // invalid until first epilogue

    for (int i = 0; i < ntiles; ++i) {
        const bool more = (i + 1 < ntiles);
        GRegs NX;
        if (more) gload(NX, xin, nbr, tile0 + i + 1, el, cq);   // prefetch
        if (i > 0) store_row(xout, eprev, cq, sv, res0, res1, lgv, lbv);

        // ---- K-loop: LDS only ----
        f32x16 acc = {};
        const u16* ab = afrag + (size_t)mt * (20 * 512);
        #pragma unroll
        for (int ks = 0; ks < 20; ++ks) {
            const bf16x8 a8 = *(const bf16x8*)(ab + (size_t)(ks * 64 + (l ^ (ks & 3))) * 8);
            const bf16x8 b8 = *(const bf16x8*)(bfrag + (size_t)(((ks * 2 + nt) * 64) + l) * 8);
            acc = __builtin_amdgcn_mfma_f32_32x32x16_bf16(a8, b8, acc, 0, 0, 0);
        }
        __syncthreads();                    // A reads done

        // ---- epilogue write: C + bias -> ebuf (aliases A) ----
        {
            const int col  = nt * 32 + (l & 31);
            const int quad = l >> 5;
            #pragma unroll
            for (int r = 0; r < 16; ++r) {
                const int row = mt * 32 + (r & 3) + 8 * (r >> 2) + 4 * quad;
                ebuf[row * 68 + col] = acc[r] + bc;
            }
        }
        __syncthreads();

        // ---- epilogue read + LN (normalized values kept in regs) ----
        {
            const float* rp = ebuf + el * 68 + cq * 16;
            float s = 0.f, qs = 0.f;
            #pragma unroll
            for (int k = 0; k < 16; ++k) { sv[k] = rp[k]; s += sv[k]; qs += sv[k] * sv[k]; }
            s  += __shfl_xor(s, 1);  s  += __shfl_xor(s, 2);
            qs += __shfl_xor(qs, 1); qs += __shfl_xor(qs, 2);
            const float mu   = s * (1.f / 64.f);
            const float var  = qs * (1.f / 64.f) - mu * mu;
            const float rinv = rsqrtf(var + LN_EPS);
            #pragma unroll
            for (int k = 0; k < 16; ++k) sv[k] = (sv[k] - mu) * rinv;
            res0 = G.xv0; res1 = G.xv1;     // residual for deferred store
            eprev = (size_t)(tile0 + i) * 128 + el;
        }
        __syncthreads();                    // ebuf reads done

        if (more) { G = NX; pack_write(G, afrag, el, cq); }
        __syncthreads();                    // A ready for next K-loop
    }
    store_row(xout, eprev, cq, sv, res0, res1, lgv, lbv);
}

// ---------------------------------------------------------------------------
// Layer 0 (MFMA, K padded 55->64): 64 edges/block, 4 waves, 17.4 KB LDS.
// ---------------------------------------------------------------------------
__global__ __launch_bounds__(256, 6) void layer0_mfma(
    const float* __restrict__ x, const int* __restrict__ nbr,
    const u16* __restrict__ wf0, const float* __restrict__ bias,
    const float* __restrict__ lng, const float* __restrict__ lnb,
    u16* __restrict__ xout)
{
    __shared__ float smem[64 * 68];
    u16* afrag = (u16*)smem;
    const int t  = threadIdx.x;
    const int l  = t & 63;
    const int wv = t >> 6;
    const int e0 = blockIdx.x * 64;
    const int el = t >> 2, cq = t & 3;

    {
        const size_t e = (size_t)(e0 + el);
        const int4 n = *(const int4*)(nbr + 4 * e);
        const float* xr = x + e * 11;
        const float* ar = x + (size_t)n.x * 11;
        const float* br = x + (size_t)n.y * 11;
        const float* cr = x + (size_t)n.z * 11;
        const float* dr = x + (size_t)n.w * 11;
        float f[16];
        if (cq == 0) {
            #pragma unroll
            for (int i = 0; i < 11; ++i) f[i] = xr[i];
            #pragma unroll
            for (int i = 0; i < 5; ++i) f[11 + i] = fabsf(ar[i] - cr[i]);
        } else if (cq == 1) {
            #pragma unroll
            for (int i = 0; i < 6; ++i) f[i] = fabsf(ar[5 + i] - cr[5 + i]);
            #pragma unroll
            for (int i = 0; i < 10; ++i) f[6 + i] = ar[i] + cr[i];
        } else if (cq == 2) {
            f[0] = ar[10] + cr[10];
            #pragma unroll
            for (int i = 0; i < 11; ++i) f[1 + i] = fabsf(br[i] - dr[i]);
            #pragma unroll
            for (int i = 0; i < 4; ++i) f[12 + i] = br[i] + dr[i];
        } else {
            #pragma unroll
            for (int i = 0; i < 7; ++i) f[i] = br[4 + i] + dr[4 + i];
            #pragma unroll
            for (int i = 7; i < 16; ++i) f[i] = 0.f;
        }
        const int mt_g  = el >> 5;
        const int lane0 = el & 31;
        u16* abase = afrag + (size_t)mt_g * (4 * 64 * 8);
        #pragma unroll
        for (int hh = 0; hh < 2; ++hh) {
            uint4 pk;
            pk.x = pk2(f[hh*8+0], f[hh*8+1]);
            pk.y = pk2(f[hh*8+2], f[hh*8+3]);
            pk.z = pk2(f[hh*8+4], f[hh*8+5]);
            pk.w = pk2(f[hh*8+6], f[hh*8+7]);
            const int gsw = (lane0 + 32 * hh) ^ cq;
            *(uint4*)(abase + (size_t)(cq * 64 + gsw) * 8) = pk;
        }
    }
    __syncthreads();

    const int mt = wv >> 1, nt = wv & 1;
    f32x16 acc = {};
    const u16* ab = afrag + (size_t)mt * (4 * 512);
    const u16* bb = wf0 + (size_t)(nt * 64 + l) * 8;
    #pragma unroll
    for (int ks = 0; ks < 4; ++ks) {
        const bf16x8 a8 = *(const bf16x8*)(ab + (size_t)(ks * 64 + (l ^ ks)) * 8);
        const bf16x8 b8 = *(const bf16x8*)(bb + ks * 1024);
        acc = __builtin_amdgcn_mfma_f32_32x32x16_bf16(a8, b8, acc, 0, 0, 0);
    }
    __syncthreads();

    float* ebuf = smem;
    {
        const int col  = nt * 32 + (l & 31);
        const int quad = l >> 5;
        const float bc = bias[col];
        #pragma unroll
        for (int r = 0; r < 16; ++r) {
            const int row = mt * 32 + (r & 3) + 8 * (r >> 2) + 4 * quad;
            ebuf[row * 68 + col] = acc[r] + bc;
        }
    }
    __syncthreads();

    {
        const float* rp = ebuf + el * 68 + cq * 16;
        float v[16];
        float s = 0.f, qs = 0.f;
        #pragma unroll
        for (int i = 0; i < 16; ++i) { v[i] = rp[i]; s += v[i]; qs += v[i] * v[i]; }
        s  += __shfl_xor(s, 1);  s  += __shfl_xor(s, 2);
        qs += __shfl_xor(qs, 1); qs += __shfl_xor(qs, 2);
        const float mu   = s * (1.f / 64.f);
        const float var  = qs * (1.f / 64.f) - mu * mu;
        const float rinv = rsqrtf(var + LN_EPS);
        const size_t e   = (size_t)(e0 + el);
        u16* outp        = xout + e * 64 + cq * 16;
        #pragma unroll
        for (int h = 0; h < 2; ++h) {
            uint4 o; unsigned* op = (unsigned*)&o;
            #pragma unroll
            for (int i = 0; i < 4; ++i) {
                const int ci = cq * 16 + h * 8 + i * 2;
                const float y0 = fmaxf(fmaf((v[h*8 + i*2]     - mu) * rinv, lng[ci],     lnb[ci]),     0.f);
                const float y1 = fmaxf(fmaf((v[h*8 + i*2 + 1] - mu) * rinv, lng[ci + 1], lnb[ci + 1]), 0.f);
                op[i] = pk2(y0, y1);
            }
            *(uint4*)(outp + h * 8) = o;
        }
    }
}

// ---------------------------------------------------------------------------
// Head (MFMA): logits = relu(x @ cw1 + cb1) @ cw2 + cb2.
// ---------------------------------------------------------------------------
__global__ __launch_bounds__(256) void head_mfma(
    const u16* __restrict__ xin,
    const float* __restrict__ cw1, const float* __restrict__ cb1,
    const float* __restrict__ cw2, const float* __restrict__ cb2,
    float* __restrict__ out)
{
    __shared__ float hbuf[4][32 * 33];
    const int t    = threadIdx.x;
    const int l    = t & 63;
    const int wv   = t >> 6;
    const int col  = l & 31;
    const int half = l >> 5;

    bf16x8 bf[4];
    #pragma unroll
    for (int ks = 0; ks < 4; ++ks) {
        const int kb = ks * 16 + half * 8;
        uint4 pk;
        pk.x = pk2(cw1[(kb+0)*32 + col], cw1[(kb+1)*32 + col]);
        pk.y = pk2(cw1[(kb+2)*32 + col], cw1[(kb+3)*32 + col]);
        pk.z = pk2(cw1[(kb+4)*32 + col], cw1[(kb+5)*32 + col]);
        pk.w = pk2(cw1[(kb+6)*32 + col], cw1[(kb+7)*32 + col]);
        __builtin_memcpy(&bf[ks], &pk, 16);
    }
    const float bc = cb1[col];
    const float w2 = cw2[col];
    const float b2 = cb2[0];

    int tile = blockIdx.x * 4 + wv;
    const int valid = tile < (E_EDGES / 32);
    if (!valid) tile = E_EDGES / 32 - 1;
    const size_t e0 = (size_t)tile * 32;
    const u16* xb = xin + (e0 + col) * 64 + half * 8;
    f32x16 acc = {};
    #pragma unroll
    for (int ks = 0; ks < 4; ++ks) {
        const bf16x8 a8 = *(const bf16x8*)(xb + ks * 16);
        acc = __builtin_amdgcn_mfma_f32_32x32x16_bf16(a8, bf[ks], acc, 0, 0, 0);
    }
    float* hb = hbuf[wv];
    #pragma unroll
    for (int r = 0; r < 16; ++r) {
        const int row = (r & 3) + 8 * (r >> 2) + 4 * half;
        hb[row * 33 + col] = fmaxf(acc[r] + bc, 0.f) * w2;
    }
    __syncthreads();
    const int row2 = l >> 1, part = l & 1;
    const float* rp = hb + row2 * 33 + part * 16;
    float s = 0.f;
    #pragma unroll
    for (int i = 0; i < 16; ++i) s += rp[i];
    s += __shfl_xor(s, 1);
    if (valid && part == 0) out[e0 + row2] = s + b2;
}

// ---------------------------------------------------------------------------
extern "C" void kernel_launch(void* const* d_in, const int* in_sizes, int n_in,
                              void* d_out, int out_size, void* d_ws, size_t ws_size,
                              hipStream_t stream)
{
    (void)in_sizes; (void)n_in; (void)out_size; (void)ws_size;
    const float* x   = (const float*)d_in[0];
    const int*   nbr = (const int*)d_in[1];
    const float* w0  = (const float*)d_in[2];
    const float* b0  = (const float*)d_in[3];
    const float* wr  = (const float*)d_in[4];
    const float* br  = (const float*)d_in[5];
    const float* lg  = (const float*)d_in[6];
    const float* lb  = (const float*)d_in[7];
    const float* cw1 = (const float*)d_in[8];
    const float* cb1 = (const float*)d_in[9];
    const float* cw2 = (const float*)d_in[10];
    const float* cb2 = (const float*)d_in[11];
    float* out = (float*)d_out;

    u16* xa = (u16*)d_ws;                       // E x 64 bf16 (128 MB)
    u16* xb = xa + (size_t)E_EDGES * 64;        // E x 64 bf16 (128 MB)
    u16* wfrag = (u16*)d_out;                   // 128 KB scratch; head overwrites d_out

    wconv_kernel<<<dim3(32), dim3(256), 0, stream>>>(wr, w0, wfrag);
    layer0_mfma<<<dim3(E_EDGES / 64), dim3(256), 0, stream>>>(x, nbr, wfrag + 3*20480, b0, lg, lb, xa);
    layer_mfma<<<dim3(256), dim3(512), 0, stream>>>(xa, nbr, wfrag,           br,        lg + 64,  lb + 64,  xb);
    layer_mfma<<<dim3(256), dim3(512), 0, stream>>>(xb, nbr, wfrag + 20480,   br + 64,   lg + 128, lb + 128, xa);
    layer_mfma<<<dim3(256), dim3(512), 0, stream>>>(xa, nbr, wfrag + 40960,   br + 128,  lg + 192, lb + 192, xb);
    head_mfma<<<dim3((E_EDGES / 32 + 3) / 4), dim3(256), 0, stream>>>(xb, cw1, cb1, cw2, cb2, out);
}